// Round 10
// baseline (30.336 us; speedup 1.0000x reference)
//
#include <hip/hip_runtime.h>

namespace {

constexpr int H = 256;
constexpr int Wd = 256;
constexpr int TILE = 16;
constexpr float EPS9 = 1e-7f / 9.0f;
constexpr float NINTH = 1.0f / 9.0f;
// s_img row pitch: 20 px * 8 ch + 4 pad (R6-validated layout).
constexpr int IPITCH = 164;
constexpr int NGROUPS = 32;

// R6 interior (champion, 18.8 us) + single-dispatch finish via a TWO-LEVEL
// completion tree: level-1 = 32 spread counters (32 pipelined adds each),
// level-2 = 1 counter (32 adds). Avoids R7's ~11 us single-address RMW tail
// (1024 serialized adds) while deleting kernel 2's dispatch + the full-grid
// retire drain between graph nodes. Modulo trick at both levels -> correct
// for ANY counter start value (0xAA poison, replays) with no reset node.
// Final reduce uses kernel-2's exact order -> bit-identical loss.
__global__ __launch_bounds__(256, 4)
void matting_loss_kernel(const float* __restrict__ content,
                         const float* __restrict__ stylized,
                         float* __restrict__ ws,
                         unsigned int* __restrict__ cnt1,   // 32, 64B apart
                         unsigned int* __restrict__ cnt2,   // 1
                         float* __restrict__ out,
                         int nblocks, float inv_denom)
{
    const int b  = blockIdx.z;
    const int x0 = blockIdx.x * TILE;
    const int y0 = blockIdx.y * TILE;
    const int tid = threadIdx.x;
    const int tx = tid & (TILE - 1);
    const int ty = tid >> 4;

    __shared__ __align__(16) float s_img[20 * IPITCH];     // [y][x*8 + m*4 + c]
    __shared__ __align__(16) float s_muk[2][18][18][4];    // mu0..2, scale
    __shared__ __align__(16) float s_A[2][18][18][6];      // a00,a01,a02,a11,a12,a22
    __shared__ float s_red[4];
    __shared__ int s_last;

    const size_t bofs = (size_t)b * 3 * H * Wd;
    const float* img0 = content + bofs;
    const float* img1 = stylized + bofs;

    // ---- Phase 1: stage 20x20 tile (+2 halo), clamped ----
    for (int p = tid; p < 400; p += 256) {
        const int py = p / 20, px = p - py * 20;
        const int gy = min(max(y0 - 2 + py, 0), H - 1);
        const int gx = min(max(x0 - 2 + px, 0), Wd - 1);
        const int gi = gy * Wd + gx;
        float4 v0, v1;
        v0.x = img0[gi]; v0.y = img0[H * Wd + gi]; v0.z = img0[2 * H * Wd + gi]; v0.w = 0.f;
        v1.x = img1[gi]; v1.y = img1[H * Wd + gi]; v1.z = img1[2 * H * Wd + gi]; v1.w = 0.f;
        float* dst = &s_img[py * IPITCH + px * 8];
        *reinterpret_cast<float4*>(dst)     = v0;
        *reinterpret_cast<float4*>(dst + 4) = v1;
    }
    __syncthreads();

    // ---- Phase 2: per-center stats (mean + inverse covariance) ----
    for (int p = tid; p < 324; p += 256) {
        const int cy = p / 18, cx = p - cy * 18;
        const int gy = y0 - 1 + cy, gx = x0 - 1 + cx;
        const bool valid = (gy >= 1) && (gy <= H - 2) && (gx >= 1) && (gx <= Wd - 2);
        const float scale = valid ? NINTH : 0.0f;
        #pragma unroll
        for (int m = 0; m < 2; ++m) {
            float s0=0.f,s1=0.f,s2=0.f,q00=0.f,q01=0.f,q02=0.f,q11=0.f,q12=0.f,q22=0.f;
            #pragma unroll
            for (int wy = 0; wy < 3; ++wy)
                #pragma unroll
                for (int wx = 0; wx < 3; ++wx) {
                    const float4 v = *reinterpret_cast<const float4*>(
                        &s_img[(cy + wy) * IPITCH + (cx + wx) * 8 + m * 4]);
                    s0 += v.x; s1 += v.y; s2 += v.z;
                    q00 += v.x * v.x; q01 += v.x * v.y; q02 += v.x * v.z;
                    q11 += v.y * v.y; q12 += v.y * v.z; q22 += v.z * v.z;
                }
            const float mu0 = s0 * NINTH, mu1 = s1 * NINTH, mu2 = s2 * NINTH;
            const float c00 = q00 * NINTH - mu0 * mu0 + EPS9;
            const float c01 = q01 * NINTH - mu0 * mu1;
            const float c02 = q02 * NINTH - mu0 * mu2;
            const float c11 = q11 * NINTH - mu1 * mu1 + EPS9;
            const float c12 = q12 * NINTH - mu1 * mu2;
            const float c22 = q22 * NINTH - mu2 * mu2 + EPS9;
            const float m00 = c11 * c22 - c12 * c12;
            const float m01 = c02 * c12 - c01 * c22;
            const float m02 = c01 * c12 - c02 * c11;
            const float det = c00 * m00 + c01 * m01 + c02 * m02;
            // invalid centers never divide; A=0 + scale=0 kills contribution.
            const float invdet = valid ? (1.0f / det) : 0.0f;
            float4 muk; muk.x = mu0; muk.y = mu1; muk.z = mu2; muk.w = scale;
            *reinterpret_cast<float4*>(&s_muk[m][cy][cx][0]) = muk;
            float* A = &s_A[m][cy][cx][0];
            float2 a0; a0.x = m00 * invdet;                  a0.y = m01 * invdet;
            float2 a1; a1.x = m02 * invdet;                  a1.y = (c00*c22 - c02*c02) * invdet;
            float2 a2; a2.x = (c01*c02 - c00*c12) * invdet;  a2.y = (c00*c11 - c01*c01) * invdet;
            reinterpret_cast<float2*>(A)[0] = a0;
            reinterpret_cast<float2*>(A)[1] = a1;
            reinterpret_cast<float2*>(A)[2] = a2;
        }
    }
    __syncthreads();

    // ---- Phase 3: sequential-image band accumulation (R6, validated) ----
    float dd[13];
    #pragma unroll
    for (int q = 0; q < 13; ++q) dd[q] = 0.f;

    #pragma unroll
    for (int m = 0; m < 2; ++m) {
        const float sign = (m == 0) ? -1.0f : 1.0f;
        const float4 Ii = *reinterpret_cast<const float4*>(
            &s_img[(ty + 2) * IPITCH + (tx + 2) * 8 + m * 4]);

        float st[3][3][3];   // [ey][ex][ch]
        float ck[3][3];
        #pragma unroll
        for (int ey = 0; ey < 3; ++ey)
        #pragma unroll
        for (int ex = 0; ex < 3; ++ex) {
            const float4 muk = *reinterpret_cast<const float4*>(&s_muk[m][ty + ey][tx + ex][0]);
            const float* Ap = &s_A[m][ty + ey][tx + ex][0];
            const float2 a0 = reinterpret_cast<const float2*>(Ap)[0];  // a00,a01
            const float2 a1 = reinterpret_cast<const float2*>(Ap)[1];  // a02,a11
            const float2 a2 = reinterpret_cast<const float2*>(Ap)[2];  // a12,a22
            const float u0 = Ii.x - muk.x, u1 = Ii.y - muk.y, u2 = Ii.z - muk.z;
            const float t0 = a0.x*u0 + a0.y*u1 + a1.x*u2;
            const float t1 = a0.y*u0 + a1.y*u1 + a2.x*u2;
            const float t2 = a1.x*u0 + a2.x*u1 + a2.y*u2;
            const float s = muk.w;
            st[ey][ex][0] = s*t0; st[ey][ex][1] = s*t1; st[ey][ex][2] = s*t2;
            ck[ey][ex] = s * (1.0f - (t0*muk.x + t1*muk.y + t2*muk.z));
        }

        #pragma unroll
        for (int by = 2; by <= 4; ++by) {
            float4 Jr[5];
            const float* jrow = &s_img[(ty + by) * IPITCH + tx * 8 + m * 4];
            #pragma unroll
            for (int q = 0; q < 5; ++q) {
                if (by == 2 && q < 2) continue;
                Jr[q] = *reinterpret_cast<const float4*>(jrow + q * 8);
            }
            float Rk[3], R[3][3];
            #pragma unroll
            for (int ex = 0; ex < 3; ++ex) {
                float rk = 0.f, r0 = 0.f, r1 = 0.f, r2 = 0.f;
                #pragma unroll
                for (int ey = 0; ey < 3; ++ey) {
                    if (ey >= by - 2) {   // compile-time after unroll
                        rk += ck[ey][ex];
                        r0 += st[ey][ex][0]; r1 += st[ey][ex][1]; r2 += st[ey][ex][2];
                    }
                }
                Rk[ex] = rk; R[ex][0] = r0; R[ex][1] = r1; R[ex][2] = r2;
            }
            #pragma unroll
            for (int bx = 0; bx < 5; ++bx) {
                if (by == 2 && bx < 2) continue;   // only bands >= center
                float Tk = 0.f, T0 = 0.f, T1 = 0.f, T2 = 0.f;
                #pragma unroll
                for (int ex = 0; ex < 3; ++ex) {
                    if (ex >= bx - 2 && ex <= bx) {
                        Tk += Rk[ex];
                        T0 += R[ex][0]; T1 += R[ex][1]; T2 += R[ex][2];
                    }
                }
                const int idx = (by - 2) * 5 + bx - 2;   // compile-time const
                const float4 J = Jr[bx];
                dd[idx] += sign * (Tk + T0 * J.x + T1 * J.y + T2 * J.z);
            }
        }
    }

    float loss = dd[0] * dd[0];            // center band, weight 1
    float loss2 = 0.f;
    #pragma unroll
    for (int q = 1; q < 13; ++q) loss2 += dd[q] * dd[q];
    loss += 2.0f * loss2;                  // symmetry weight

    // ---- Phase 4: block reduce -> ws store -> two-level completion tree ----
    #pragma unroll
    for (int off = 32; off >= 1; off >>= 1)
        loss += __shfl_down(loss, off, 64);
    if ((tid & 63) == 0) s_red[tid >> 6] = loss;
    __syncthreads();

    const int bid = (blockIdx.z * gridDim.y + blockIdx.y) * gridDim.x + blockIdx.x;
    if (tid == 0) {
        s_last = 0;
        ws[bid] = s_red[0] + s_red[1] + s_red[2] + s_red[3];
        __threadfence();                               // release partial
        const unsigned int gsz = (unsigned)(nblocks / NGROUPS);
        const int g = bid & (NGROUPS - 1);
        const unsigned int o1 = atomicAdd(&cnt1[g * 16], 1u);   // 64B-spread
        if (o1 % gsz == gsz - 1) {                     // last of my group
            __threadfence();
            const unsigned int o2 = atomicAdd(cnt2, 1u);
            if (o2 % NGROUPS == NGROUPS - 1)           // last group overall
                s_last = 1;
        }
    }
    __syncthreads();

    if (s_last) {
        __threadfence();   // acquire: all partials visible
        float acc = 0.f;
        for (int i = tid; i < nblocks; i += 256) acc += ws[i];
        #pragma unroll
        for (int off = 32; off >= 1; off >>= 1)
            acc += __shfl_down(acc, off, 64);
        if ((tid & 63) == 0) s_red[tid >> 6] = acc;
        __syncthreads();
        if (tid == 0)
            out[0] = (s_red[0] + s_red[1] + s_red[2] + s_red[3]) * inv_denom;
    }
}

} // namespace

extern "C" void kernel_launch(void* const* d_in, const int* in_sizes, int n_in,
                              void* d_out, int out_size, void* d_ws, size_t ws_size,
                              hipStream_t stream) {
    const float* content  = (const float*)d_in[0];
    const float* stylized = (const float*)d_in[1];
    float* out = (float*)d_out;
    float* ws  = (float*)d_ws;                                   // 1024 partials
    unsigned int* cnt1 = (unsigned int*)((char*)d_ws + 8192);    // 32 x 64B-spread
    unsigned int* cnt2 = (unsigned int*)((char*)d_ws + 12288);   // 1

    const int B = in_sizes[0] / (3 * H * Wd);
    const float inv_denom =
        1.0f / ((float)B * (float)(H * Wd) * (float)(H * Wd));

    dim3 grid(Wd / TILE, H / TILE, B);
    const int nblocks = grid.x * grid.y * grid.z;
    matting_loss_kernel<<<grid, 256, 0, stream>>>(content, stylized, ws,
                                                  cnt1, cnt2, out, nblocks, inv_denom);
}

// Round 11
// 17.082 us; speedup vs baseline: 1.7760x; 1.7760x over previous
//
#include <hip/hip_runtime.h>

namespace {

constexpr int H = 256;
constexpr int Wd = 256;
constexpr int TILE = 16;
constexpr float EPS9 = 1e-7f / 9.0f;
constexpr float NINTH = 1.0f / 9.0f;
// s_img row pitch: 20 px * 8 ch + 4 pad (R6-validated layout).
constexpr int IPITCH = 164;
constexpr int NGROUPS = 32;   // completion-tree fan-in (1024 = 32 x 32)

// R6 interior (champion) + FENCE-FREE single-dispatch finish.
// R7/R10 post-mortem: the fused finish cost ~11.5 us with per-block
// __threadfence (emits L2 writeback per block); counter spreading was
// irrelevant. Here: partials published via relaxed AGENT-scope atomic
// stores (write through to the coherence point, no fence), ordered before
// the completion-tree atomics by a single vmcnt(0); last block reads them
// back via relaxed agent-scope atomic loads (coherent, no acquire fence)
// and sums in kernel-2's exact order -> bit-identical to R6's result.
// Counters use the modulo trick (exactly +32 / +32 per launch at each
// level) -> correct for ANY poisoned start value, no reset node.
__global__ __launch_bounds__(256, 4)
void matting_loss_kernel(const float* __restrict__ content,
                         const float* __restrict__ stylized,
                         float* __restrict__ ws,
                         unsigned int* __restrict__ cnt1,   // 32, 64B apart
                         unsigned int* __restrict__ cnt2,   // 1
                         float* __restrict__ out,
                         int nblocks, float inv_denom)
{
    const int b  = blockIdx.z;
    const int x0 = blockIdx.x * TILE;
    const int y0 = blockIdx.y * TILE;
    const int tid = threadIdx.x;
    const int tx = tid & (TILE - 1);
    const int ty = tid >> 4;

    __shared__ __align__(16) float s_img[20 * IPITCH];     // [y][x*8 + m*4 + c]
    __shared__ __align__(16) float s_muk[2][18][18][4];    // mu0..2, scale
    __shared__ __align__(16) float s_A[2][18][18][6];      // a00,a01,a02,a11,a12,a22
    __shared__ float s_red[4];
    __shared__ int s_last;

    const size_t bofs = (size_t)b * 3 * H * Wd;
    const float* img0 = content + bofs;
    const float* img1 = stylized + bofs;

    // ---- Phase 1: stage 20x20 tile (+2 halo), clamped ----
    for (int p = tid; p < 400; p += 256) {
        const int py = p / 20, px = p - py * 20;
        const int gy = min(max(y0 - 2 + py, 0), H - 1);
        const int gx = min(max(x0 - 2 + px, 0), Wd - 1);
        const int gi = gy * Wd + gx;
        float4 v0, v1;
        v0.x = img0[gi]; v0.y = img0[H * Wd + gi]; v0.z = img0[2 * H * Wd + gi]; v0.w = 0.f;
        v1.x = img1[gi]; v1.y = img1[H * Wd + gi]; v1.z = img1[2 * H * Wd + gi]; v1.w = 0.f;
        float* dst = &s_img[py * IPITCH + px * 8];
        *reinterpret_cast<float4*>(dst)     = v0;
        *reinterpret_cast<float4*>(dst + 4) = v1;
    }
    __syncthreads();

    // ---- Phase 2: per-center stats (mean + inverse covariance) ----
    for (int p = tid; p < 324; p += 256) {
        const int cy = p / 18, cx = p - cy * 18;
        const int gy = y0 - 1 + cy, gx = x0 - 1 + cx;
        const bool valid = (gy >= 1) && (gy <= H - 2) && (gx >= 1) && (gx <= Wd - 2);
        const float scale = valid ? NINTH : 0.0f;
        #pragma unroll
        for (int m = 0; m < 2; ++m) {
            float s0=0.f,s1=0.f,s2=0.f,q00=0.f,q01=0.f,q02=0.f,q11=0.f,q12=0.f,q22=0.f;
            #pragma unroll
            for (int wy = 0; wy < 3; ++wy)
                #pragma unroll
                for (int wx = 0; wx < 3; ++wx) {
                    const float4 v = *reinterpret_cast<const float4*>(
                        &s_img[(cy + wy) * IPITCH + (cx + wx) * 8 + m * 4]);
                    s0 += v.x; s1 += v.y; s2 += v.z;
                    q00 += v.x * v.x; q01 += v.x * v.y; q02 += v.x * v.z;
                    q11 += v.y * v.y; q12 += v.y * v.z; q22 += v.z * v.z;
                }
            const float mu0 = s0 * NINTH, mu1 = s1 * NINTH, mu2 = s2 * NINTH;
            const float c00 = q00 * NINTH - mu0 * mu0 + EPS9;
            const float c01 = q01 * NINTH - mu0 * mu1;
            const float c02 = q02 * NINTH - mu0 * mu2;
            const float c11 = q11 * NINTH - mu1 * mu1 + EPS9;
            const float c12 = q12 * NINTH - mu1 * mu2;
            const float c22 = q22 * NINTH - mu2 * mu2 + EPS9;
            const float m00 = c11 * c22 - c12 * c12;
            const float m01 = c02 * c12 - c01 * c22;
            const float m02 = c01 * c12 - c02 * c11;
            const float det = c00 * m00 + c01 * m01 + c02 * m02;
            // invalid centers never divide; A=0 + scale=0 kills contribution.
            const float invdet = valid ? (1.0f / det) : 0.0f;
            float4 muk; muk.x = mu0; muk.y = mu1; muk.z = mu2; muk.w = scale;
            *reinterpret_cast<float4*>(&s_muk[m][cy][cx][0]) = muk;
            float* A = &s_A[m][cy][cx][0];
            float2 a0; a0.x = m00 * invdet;                  a0.y = m01 * invdet;
            float2 a1; a1.x = m02 * invdet;                  a1.y = (c00*c22 - c02*c02) * invdet;
            float2 a2; a2.x = (c01*c02 - c00*c12) * invdet;  a2.y = (c00*c11 - c01*c01) * invdet;
            reinterpret_cast<float2*>(A)[0] = a0;
            reinterpret_cast<float2*>(A)[1] = a1;
            reinterpret_cast<float2*>(A)[2] = a2;
        }
    }
    __syncthreads();

    // ---- Phase 3: sequential-image band accumulation (R6, validated) ----
    float dd[13];
    #pragma unroll
    for (int q = 0; q < 13; ++q) dd[q] = 0.f;

    #pragma unroll
    for (int m = 0; m < 2; ++m) {
        const float sign = (m == 0) ? -1.0f : 1.0f;
        const float4 Ii = *reinterpret_cast<const float4*>(
            &s_img[(ty + 2) * IPITCH + (tx + 2) * 8 + m * 4]);

        float st[3][3][3];   // [ey][ex][ch]
        float ck[3][3];
        #pragma unroll
        for (int ey = 0; ey < 3; ++ey)
        #pragma unroll
        for (int ex = 0; ex < 3; ++ex) {
            const float4 muk = *reinterpret_cast<const float4*>(&s_muk[m][ty + ey][tx + ex][0]);
            const float* Ap = &s_A[m][ty + ey][tx + ex][0];
            const float2 a0 = reinterpret_cast<const float2*>(Ap)[0];  // a00,a01
            const float2 a1 = reinterpret_cast<const float2*>(Ap)[1];  // a02,a11
            const float2 a2 = reinterpret_cast<const float2*>(Ap)[2];  // a12,a22
            const float u0 = Ii.x - muk.x, u1 = Ii.y - muk.y, u2 = Ii.z - muk.z;
            const float t0 = a0.x*u0 + a0.y*u1 + a1.x*u2;
            const float t1 = a0.y*u0 + a1.y*u1 + a2.x*u2;
            const float t2 = a1.x*u0 + a2.x*u1 + a2.y*u2;
            const float s = muk.w;
            st[ey][ex][0] = s*t0; st[ey][ex][1] = s*t1; st[ey][ex][2] = s*t2;
            ck[ey][ex] = s * (1.0f - (t0*muk.x + t1*muk.y + t2*muk.z));
        }

        #pragma unroll
        for (int by = 2; by <= 4; ++by) {
            float4 Jr[5];
            const float* jrow = &s_img[(ty + by) * IPITCH + tx * 8 + m * 4];
            #pragma unroll
            for (int q = 0; q < 5; ++q) {
                if (by == 2 && q < 2) continue;
                Jr[q] = *reinterpret_cast<const float4*>(jrow + q * 8);
            }
            float Rk[3], R[3][3];
            #pragma unroll
            for (int ex = 0; ex < 3; ++ex) {
                float rk = 0.f, r0 = 0.f, r1 = 0.f, r2 = 0.f;
                #pragma unroll
                for (int ey = 0; ey < 3; ++ey) {
                    if (ey >= by - 2) {   // compile-time after unroll
                        rk += ck[ey][ex];
                        r0 += st[ey][ex][0]; r1 += st[ey][ex][1]; r2 += st[ey][ex][2];
                    }
                }
                Rk[ex] = rk; R[ex][0] = r0; R[ex][1] = r1; R[ex][2] = r2;
            }
            #pragma unroll
            for (int bx = 0; bx < 5; ++bx) {
                if (by == 2 && bx < 2) continue;   // only bands >= center
                float Tk = 0.f, T0 = 0.f, T1 = 0.f, T2 = 0.f;
                #pragma unroll
                for (int ex = 0; ex < 3; ++ex) {
                    if (ex >= bx - 2 && ex <= bx) {
                        Tk += Rk[ex];
                        T0 += R[ex][0]; T1 += R[ex][1]; T2 += R[ex][2];
                    }
                }
                const int idx = (by - 2) * 5 + bx - 2;   // compile-time const
                const float4 J = Jr[bx];
                dd[idx] += sign * (Tk + T0 * J.x + T1 * J.y + T2 * J.z);
            }
        }
    }

    float loss = dd[0] * dd[0];            // center band, weight 1
    float loss2 = 0.f;
    #pragma unroll
    for (int q = 1; q < 13; ++q) loss2 += dd[q] * dd[q];
    loss += 2.0f * loss2;                  // symmetry weight

    // ---- Phase 4: block reduce -> coherent publish -> completion tree ----
    #pragma unroll
    for (int off = 32; off >= 1; off >>= 1)
        loss += __shfl_down(loss, off, 64);
    if ((tid & 63) == 0) s_red[tid >> 6] = loss;
    __syncthreads();

    const int bid = (blockIdx.z * gridDim.y + blockIdx.y) * gridDim.x + blockIdx.x;
    if (tid == 0) {
        s_last = 0;
        const float partial = s_red[0] + s_red[1] + s_red[2] + s_red[3];
        // Publish at the coherence point (no L2-writeback fence needed).
        __hip_atomic_store(&ws[bid], partial, __ATOMIC_RELAXED,
                           __HIP_MEMORY_SCOPE_AGENT);
        // Order the publish before the completion-tree atomics.
        asm volatile("s_waitcnt vmcnt(0)" ::: "memory");
        const unsigned int gsz = (unsigned)(nblocks / NGROUPS);   // 32
        const int g = bid & (NGROUPS - 1);
        const unsigned int o1 = atomicAdd(&cnt1[g * 16], 1u);     // 64B-spread
        if (o1 % gsz == gsz - 1) {                     // last of my group
            const unsigned int o2 = atomicAdd(cnt2, 1u);
            if (o2 % NGROUPS == NGROUPS - 1)           // last group overall
                s_last = 1;
        }
    }
    __syncthreads();

    if (s_last) {
        // Coherent reads of all partials (agent-scope, bypass stale caches),
        // summed in kernel-2's exact order -> bit-identical result.
        float acc = 0.f;
        for (int i = tid; i < nblocks; i += 256)
            acc += __hip_atomic_load(&ws[i], __ATOMIC_RELAXED,
                                     __HIP_MEMORY_SCOPE_AGENT);
        #pragma unroll
        for (int off = 32; off >= 1; off >>= 1)
            acc += __shfl_down(acc, off, 64);
        if ((tid & 63) == 0) s_red[tid >> 6] = acc;
        __syncthreads();
        if (tid == 0)
            out[0] = (s_red[0] + s_red[1] + s_red[2] + s_red[3]) * inv_denom;
    }
}

} // namespace

extern "C" void kernel_launch(void* const* d_in, const int* in_sizes, int n_in,
                              void* d_out, int out_size, void* d_ws, size_t ws_size,
                              hipStream_t stream) {
    const float* content  = (const float*)d_in[0];
    const float* stylized = (const float*)d_in[1];
    float* out = (float*)d_out;
    float* ws  = (float*)d_ws;                                   // 1024 partials
    unsigned int* cnt1 = (unsigned int*)((char*)d_ws + 8192);    // 32 x 64B-spread
    unsigned int* cnt2 = (unsigned int*)((char*)d_ws + 12288);   // 1

    const int B = in_sizes[0] / (3 * H * Wd);
    const float inv_denom =
        1.0f / ((float)B * (float)(H * Wd) * (float)(H * Wd));

    dim3 grid(Wd / TILE, H / TILE, B);
    const int nblocks = grid.x * grid.y * grid.z;
    matting_loss_kernel<<<grid, 256, 0, stream>>>(content, stylized, ws,
                                                  cnt1, cnt2, out, nblocks, inv_denom);
}